// Round 6
// baseline (9317.918 us; speedup 1.0000x reference)
//
#include <hip/hip_runtime.h>
#include <stdint.h>

// ---------------------------------------------------------------------------
// 2-layer GRU, B=128, T=1024, H=IN=256, OUT=128.  Dtype probed on device.
//
// v11: MFMA with the M-dimension FILLED (16 batches/block), v6-grade rings.
//  - v10 post-mortem: M=2 in a 16-tile left 48/64 lanes idle for all ring /
//    activation work and made publishes 16-lane strided -> WRITE_SIZE 2x
//    (partial lines), latency-bound at 3.9ms.  v8 post-mortem: lane-major
//    ring layout + tag-per-u32 HR + 32 spins/lane -> 15ms.
//  - Grid: 8 groups x 16 batches, 4 roles (L0X,L0H,L1X,L1H) = 32 blocks
//    x 512 thr (8 waves).  Per role-step: one (16 x 768 x 256) GEMM =
//    48 mfma_f32_16x16x32_f16 per wave.  Every D element meaningful.
//  - Rings (4 slots, in-band tags, relaxed-agent atomics, v6 protocol):
//      XR: [slot][b:16][u:256] u64 {f16 sr,sz | f16 sn, tag16}  (32KB/slot)
//      HR: [slot][b:16][j:128] u64 {f16 h2j,h2j+1 | tag32}      (16KB/slot)
//    Publish/consume instructions are 64-lane dense (4 x 128B segments).
//  - A-matrix (x or h) staged in LDS, rows=batch, 512B/row f16, XOR swizzle
//    byte ^= ((row&7)<<4) (v8-verified); frag read = 2-way bank alias (free).
//  - Weights: 48 B-frags/lane = 36 in regs + 12 in LDS (v8-verified split,
//    fits 256 unified regs at 2 waves/SIMD; MFMA reads AGPR operands free).
//  - Frag conventions (verified in v8 AND v10, both passed): A row=lane&15,
//    k0=32kk+8lq; B row = weight row; D col=lane&15 (unit), row=4lq+i (batch).
// ---------------------------------------------------------------------------

// ws layout in dwords (same footprint as v6)
#define XR0_OFF 0            // [8 grp][4 slot][16 b][256 u] u64 = 262144 dw
#define XR1_OFF 262144
#define HR0_OFF 524288       // [8 grp][4 slot][16 b][128 j] u64 = 131072 dw
#define CTR_OFF 655360       // u32 [4 role][64][16]
#define FLG_OFF 659456

typedef _Float16 half8 __attribute__((ext_vector_type(8)));
typedef float    f32x4 __attribute__((ext_vector_type(4)));
typedef float    f4v   __attribute__((ext_vector_type(4)));
typedef _Float16 h2_t  __attribute__((ext_vector_type(2)));
union H2U { uint32_t u; h2_t h; };
union FU  { uint32_t u; float f; };

__device__ __forceinline__ float bf2f(uint16_t b){ FU v; v.u=(uint32_t)b<<16; return v.f; }
__device__ __forceinline__ uint16_t f2bf(float f){
    FU v; v.f=f; uint32_t r=v.u+0x7fffu+((v.u>>16)&1u); return (uint16_t)(r>>16);
}
__device__ __forceinline__ float rcp_f(float x){ return __builtin_amdgcn_rcpf(x); }
__device__ __forceinline__ float sigmoid_f(float x){ return rcp_f(1.0f+__expf(-x)); }
__device__ __forceinline__ float tanh_f(float x){
    float ax=fabsf(x); float e=__expf(-2.0f*ax);
    float t=(1.0f-e)*rcp_f(1.0f+e); return x<0.0f?-t:t;
}
__device__ __forceinline__ uint32_t bfpair_to_h2(uint32_t raw){
    FU lo,hi; lo.u=raw<<16; hi.u=raw&0xffff0000u;
    H2U r; r.h[0]=(_Float16)lo.f; r.h[1]=(_Float16)hi.f; return r.u;
}
__device__ __forceinline__ uint32_t f2_to_h2(float a, float b){
    H2U r; r.h[0]=(_Float16)a; r.h[1]=(_Float16)b; return r.u;
}
__device__ __forceinline__ float hbits2f(uint32_t bits){
    H2U t; t.u = bits & 0xffffu; return (float)t.h[0];
}

#define RLX_LD(p)    __hip_atomic_load((p),        __ATOMIC_RELAXED, __HIP_MEMORY_SCOPE_AGENT)
#define RLX_ST(p,v)  __hip_atomic_store((p), (v),  __ATOMIC_RELAXED, __HIP_MEMORY_SCOPE_AGENT)
__device__ __forceinline__ uint64_t RLX_LD64(const uint64_t* p){
    return __hip_atomic_load(p, __ATOMIC_RELAXED, __HIP_MEMORY_SCOPE_AGENT);
}
__device__ __forceinline__ void RLX_ST64(uint64_t* p, uint64_t v){
    __hip_atomic_store(p, v, __ATOMIC_RELAXED, __HIP_MEMORY_SCOPE_AGENT);
}

// LDS-only barrier (ring publishes drain under compute; rings tag-protected)
#define BAR() do {                                              \
    asm volatile("s_waitcnt lgkmcnt(0)" ::: "memory");          \
    __builtin_amdgcn_s_barrier();                               \
    asm volatile("" ::: "memory");                              \
} while (0)

__device__ __forceinline__ f32x4 MFMA16(uint4 a, uint4 b, f32x4 c){
    half8 A = __builtin_bit_cast(half8, a);
    half8 B = __builtin_bit_cast(half8, b);
    return __builtin_amdgcn_mfma_f32_16x16x32_f16(A, B, c, 0, 0, 0);
}

// B-frag: 8 consecutive k (f16) of weight row `row` (row-major [*][256])
__device__ __forceinline__ uint4 ldfrag16(const void* W, int isbf, int row, int k0){
    if (isbf){
        uint4 raw = *(const uint4*)((const uint16_t*)W + (size_t)row*256 + k0);
        raw.x = bfpair_to_h2(raw.x); raw.y = bfpair_to_h2(raw.y);
        raw.z = bfpair_to_h2(raw.z); raw.w = bfpair_to_h2(raw.w);
        return raw;
    } else {
        const float* p = (const float*)W + (size_t)row*256 + k0;
        f4v f0 = *(const f4v*)p, f1 = *(const f4v*)(p+4);
        uint4 r;
        r.x = f2_to_h2(f0[0],f0[1]); r.y = f2_to_h2(f0[2],f0[3]);
        r.z = f2_to_h2(f1[0],f1[1]); r.w = f2_to_h2(f1[2],f1[3]);
        return r;
    }
}

__global__ void probe_init(const uint32_t* __restrict__ w,
                           uint32_t* __restrict__ ctr,
                           uint32_t* __restrict__ flag) {
    int i = threadIdx.x;
    for (int k = i; k < 4096; k += 1024) ctr[k] = 0u;
    if (i == 0) {
        int c = 0;
        for (int j = 0; j < 64; ++j) {
            uint32_t e = (w[j] >> 7) & 0xFFu;
            c += (e >= 0x60u && e <= 0x7Cu) ? 1 : 0;
        }
        flag[0] = (c >= 32) ? 1u : 0u;
    }
}

template<bool ISBF>
__device__ __forceinline__ void gru_body(
    const void* xin,
    const void* Wx0, const void* bx0, const void* Wh0, const void* bh0,
    const void* Wx1, const void* bx1, const void* Wh1, const void* bh1,
    const void* Wo,  const void* bo,  void* out, uint32_t* ws, char* smem)
{
    const int tid = threadIdx.x;
    const int grp  = blockIdx.x & 7;
    const int role = blockIdx.x >> 3;
    const int w  = tid >> 6;         // wave 0..7 -> units [32w, 32w+32)
    const int l  = tid & 63;
    const int lr = l & 15;           // A-row(batch) on input / D-col(unit)
    const int lq = l >> 4;

    uint64_t* XR0p = (uint64_t*)(ws + XR0_OFF) + (size_t)grp * 16384;  // 4x4096
    uint64_t* XR1p = (uint64_t*)(ws + XR1_OFF) + (size_t)grp * 16384;
    uint64_t* HRp  = (uint64_t*)(ws + HR0_OFF) + (size_t)grp * 8192;   // 4x2048
    uint32_t* CTR  = ws + CTR_OFF;
    uint32_t* myprg   = CTR + role * 1024 + grp * 16;
    uint32_t* consprg = CTR + (role + 1) * 1024 + grp * 16;

    const void* Wsel; const void* bsel;
    if      (role == 0) { Wsel = Wx0; bsel = bx0; }
    else if (role == 1) { Wsel = Wh0; bsel = bh0; }
    else if (role == 2) { Wsel = Wx1; bsel = bx1; }
    else                { Wsel = Wh1; bsel = bh1; }

    uint4* wl  = (uint4*)smem;              // 12 x 512 x 16B = 98304
    char*  stg = smem + 98304;              // 2 buf x 16 rows x 512B = 16384
    const int isbf = ISBF ? 1 : 0;

    // 48 B-frags (36 reg / 12 LDS) + bias
    uint4 breg[36];
    float bias[6];
#pragma unroll
    for (int g = 0; g < 3; ++g)
#pragma unroll
        for (int m = 0; m < 2; ++m) {
            int row = g * 256 + 32 * w + 16 * m + lr;
            bias[g*2+m] = ISBF ? bf2f(((const uint16_t*)bsel)[row])
                               : ((const float*)bsel)[row];
#pragma unroll
            for (int kk = 0; kk < 8; ++kk) {
                int f = g * 16 + m * 8 + kk;
                uint4 bv = ldfrag16(Wsel, isbf, row, 32 * kk + 8 * lq);
                if (f < 36) breg[f] = bv;
                else        wl[(f - 36) * 512 + tid] = bv;
            }
        }

#define GETB(f) ((f) < 36 ? breg[(f)] : wl[((f) - 36) * 512 + tid])

#define DO_MFMA(acc, afr)                                                   \
    _Pragma("unroll")                                                       \
    for (int kk = 0; kk < 8; ++kk)                                          \
        _Pragma("unroll")                                                   \
        for (int g = 0; g < 3; ++g)                                         \
            _Pragma("unroll")                                               \
            for (int m = 0; m < 2; ++m)                                     \
                acc[g*2+m] = MFMA16(afr[kk], GETB(g*16+m*8+kk), acc[g*2+m]);

#define LOAD_AFR(afr, bufbase)                                              \
    _Pragma("unroll")                                                       \
    for (int kk = 0; kk < 8; ++kk)                                          \
        afr[kk] = *(const uint4*)((bufbase) + lr * 512 +                    \
                                  ((64 * kk + 16 * lq) ^ ((lr & 7) << 4)));

    uint32_t prog_seen = 0;

    if (role == 0 || role == 2) {
        // ============================ X stages =============================
        uint64_t* outring = (role == 0) ? XR0p : XR1p;
        // X0 staging identities
        const int xrow = tid >> 5, xseg = tid & 31;
        uint4 xp0, xp1;
        uint64_t pf[4]; pf[0]=pf[1]=pf[2]=pf[3]=0;

        if (role == 0) {   // prefetch x(0)
            size_t base = ((size_t)(grp*16 + xrow) * 1024 + 0) * 256 + xseg * 8;
            if (ISBF) xp0 = *(const uint4*)((const uint16_t*)xin + base);
            else { const float* p = (const float*)xin + base;
                   xp0 = *(const uint4*)p; xp1 = *(const uint4*)(p + 4); }
        }

        for (int t = 0; t < 1024; ++t) {
            if (t >= 4 && prog_seen + 3 < (uint32_t)t) {     // ring-wrap guard
                do { prog_seen = RLX_LD(consprg);
                     if (prog_seen + 3 < (uint32_t)t) __builtin_amdgcn_s_sleep(2);
                } while (prog_seen + 3 < (uint32_t)t);
            }
            char* buf = stg + (t & 1) * 8192;
            if (role == 0) {
                // stage x(t): row=batch, f16, swizzled
                uint4 v;
                if (ISBF) { v.x = bfpair_to_h2(xp0.x); v.y = bfpair_to_h2(xp0.y);
                            v.z = bfpair_to_h2(xp0.z); v.w = bfpair_to_h2(xp0.w); }
                else {
                    f4v f0 = __builtin_bit_cast(f4v, xp0), f1 = __builtin_bit_cast(f4v, xp1);
                    v.x = f2_to_h2(f0[0],f0[1]); v.y = f2_to_h2(f0[2],f0[3]);
                    v.z = f2_to_h2(f1[0],f1[1]); v.w = f2_to_h2(f1[2],f1[3]);
                }
                *(uint4*)(buf + xrow * 512 + ((xseg * 16) ^ ((xrow & 7) << 4))) = v;
            } else {
                // consume h0(t) from HR: 4 entries/thread, coalesced
#pragma unroll
                for (int k = 0; k < 4; ++k) {
                    int idx = k * 512 + tid;
                    uint64_t u = pf[k];
                    const uint64_t* a = HRp + (size_t)(t & 3) * 2048 + idx;
                    while ((uint32_t)(u >> 32) != (uint32_t)(t + 1)) {
                        __builtin_amdgcn_s_sleep(1);
                        u = RLX_LD64(a);
                    }
                    int b = idx >> 7, j = idx & 127;
                    *(uint32_t*)(buf + b * 512 + ((j * 4) ^ ((b & 7) << 4))) = (uint32_t)u;
                }
            }
            BAR();
            if (tid == 0 && !(t & 1)) RLX_ST(myprg, (uint32_t)t);
            if (t < 1023) {                                  // prefetch t+1
                if (role == 0) {
                    size_t base = ((size_t)(grp*16 + xrow) * 1024 + (t + 1)) * 256 + xseg * 8;
                    if (ISBF) xp0 = *(const uint4*)((const uint16_t*)xin + base);
                    else { const float* p = (const float*)xin + base;
                           xp0 = *(const uint4*)p; xp1 = *(const uint4*)(p + 4); }
                } else {
#pragma unroll
                    for (int k = 0; k < 4; ++k)
                        pf[k] = RLX_LD64(HRp + (size_t)((t + 1) & 3) * 2048 + k * 512 + tid);
                }
            }
            uint4 afr[8];
            LOAD_AFR(afr, buf);
            f32x4 acc[6];
#pragma unroll
            for (int i6 = 0; i6 < 6; ++i6)
                acc[i6] = (f32x4){bias[i6], bias[i6], bias[i6], bias[i6]};
            DO_MFMA(acc, afr);
            // publish: entry (b=4lq+i, u=32w+16m+lr) -- 64-lane dense stores
            const uint32_t want = (uint32_t)(t + 1);
            uint64_t* slot = outring + (size_t)(t & 3) * 4096;
#pragma unroll
            for (int m = 0; m < 2; ++m)
#pragma unroll
                for (int i = 0; i < 4; ++i) {
                    H2U lo; lo.h[0] = (_Float16)acc[m][i]; lo.h[1] = (_Float16)acc[2+m][i];
                    H2U hn; hn.u = 0; hn.h[0] = (_Float16)acc[4+m][i];
                    uint32_t hi = (hn.u & 0xFFFFu) | (want << 16);
                    RLX_ST64(slot + (size_t)(4*lq + i) * 256 + 32*w + 16*m + lr,
                             (uint64_t)lo.u | ((uint64_t)hi << 32));
                }
        }
        if (tid == 0) RLX_ST(myprg, 1024u);
    } else {
        // ============================ H stages =============================
        const uint64_t* xr = (role == 1) ? XR0p : XR1p;
        for (int i = tid; i < 4096; i += 512) ((uint32_t*)stg)[i] = 0u;  // h(0)=0
        float h8[8];
#pragma unroll
        for (int e = 0; e < 8; ++e) h8[e] = 0.f;
        uint64_t cur[8];
#pragma unroll
        for (int e = 0; e < 8; ++e) cur[e] = 0;

        for (int t = 0; t < 1024; ++t) {
            if (role == 1 && t >= 4 && prog_seen + 3 < (uint32_t)t) {
                do { prog_seen = RLX_LD(consprg);
                     if (prog_seen + 3 < (uint32_t)t) __builtin_amdgcn_s_sleep(2);
                } while (prog_seen + 3 < (uint32_t)t);
            }
            const uint32_t want = (uint32_t)(t + 1);
            const uint64_t* slot = xr + (size_t)(t & 3) * 4096;
#pragma unroll
            for (int m = 0; m < 2; ++m)
#pragma unroll
                for (int i = 0; i < 4; ++i) {
                    int e = m * 4 + i;
                    if ((uint32_t)(cur[e] >> 48) != want) {
                        const uint64_t* a = slot + (size_t)(4*lq + i) * 256 + 32*w + 16*m + lr;
                        uint64_t u;
                        do { u = RLX_LD64(a);
                             if ((uint32_t)(u >> 48) != want) __builtin_amdgcn_s_sleep(1);
                        } while ((uint32_t)(u >> 48) != want);
                        cur[e] = u;
                    }
                }
            BAR();                       // h(t) LDS writes (prev iter) visible
            if (tid == 0 && !(t & 1)) RLX_ST(myprg, (uint32_t)t);
            float srv[8], szv[8], snv[8];
#pragma unroll
            for (int e = 0; e < 8; ++e) {
                uint32_t loq = (uint32_t)cur[e];
                srv[e] = hbits2f(loq);
                szv[e] = hbits2f(loq >> 16);
                snv[e] = hbits2f((uint32_t)(cur[e] >> 32));
            }
            if (t < 1023) {              // prefetch t+1
                const uint64_t* nslot = xr + (size_t)((t + 1) & 3) * 4096;
#pragma unroll
                for (int m = 0; m < 2; ++m)
#pragma unroll
                    for (int i = 0; i < 4; ++i)
                        cur[m*4+i] = RLX_LD64(nslot + (size_t)(4*lq + i) * 256 + 32*w + 16*m + lr);
            }
            char* buf = stg + (t & 1) * 8192;
            uint4 afr[8];
            LOAD_AFR(afr, buf);
            f32x4 acc[6];
#pragma unroll
            for (int i6 = 0; i6 < 6; ++i6)
                acc[i6] = (f32x4){bias[i6], bias[i6], bias[i6], bias[i6]};
            DO_MFMA(acc, afr);
            // activations (all 64 lanes, 8 units each) + h-write + HR publish
            char* nbuf = stg + ((t + 1) & 1) * 8192;
#pragma unroll
            for (int m = 0; m < 2; ++m)
#pragma unroll
                for (int i = 0; i < 4; ++i) {
                    int e = m * 4 + i;
                    float r = sigmoid_f(srv[e] + acc[m][i]);
                    float z = sigmoid_f(szv[e] + acc[2+m][i]);
                    float n = tanh_f  (snv[e] + r * acc[4+m][i]);
                    h8[e] = z * h8[e] + (1.0f - z) * n;
                }
#pragma unroll
            for (int m = 0; m < 2; ++m)
#pragma unroll
                for (int i = 0; i < 4; ++i) {
                    int e = m * 4 + i;
                    float hp = __shfl_xor(h8[e], 1);
                    if (!(lr & 1)) {
                        uint32_t pk = f2_to_h2(h8[e], hp);
                        int b  = 4 * lq + i;
                        int jj = 16 * w + 8 * m + (lr >> 1);
                        *(uint32_t*)(nbuf + b * 512 + ((jj * 4) ^ ((b & 7) << 4))) = pk;
                        if (role == 1)
                            RLX_ST64(HRp + (size_t)(t & 3) * 2048 + b * 128 + jj,
                                     (uint64_t)pk | ((uint64_t)want << 32));
                    }
                }
        }
        BAR();
        if (tid == 0) RLX_ST(myprg, 1024u);

        // ---------------- epilogue (role 3): out = h1.Wo^T + bo ------------
        if (role == 3) {
            uint4 afr[8];
            LOAD_AFR(afr, stg);          // final h1 in buffer 0 (1024 even)
            int col = 16 * w + lr;       // OUT=128 = 8 waves x 16
            float bc = ISBF ? bf2f(((const uint16_t*)bo)[col]) : ((const float*)bo)[col];
            f32x4 accO = (f32x4){bc, bc, bc, bc};
#pragma unroll
            for (int kk = 0; kk < 8; ++kk) {
                uint4 bv = ldfrag16(Wo, isbf, col, 32 * kk + 8 * lq);
                accO = MFMA16(afr[kk], bv, accO);
            }
#pragma unroll
            for (int i = 0; i < 4; ++i) {
                size_t oi = (size_t)(grp * 16 + 4 * lq + i) * 128 + col;
                if (ISBF) ((uint16_t*)out)[oi] = f2bf(accO[i]);
                else      ((float*)out)[oi]    = accO[i];
            }
        }
    }
#undef GETB
#undef DO_MFMA
#undef LOAD_AFR
}

__global__ void __launch_bounds__(512, 2)
gru12(const void* __restrict__ xin,
      const void* __restrict__ Wx0, const void* __restrict__ bx0,
      const void* __restrict__ Wh0, const void* __restrict__ bh0,
      const void* __restrict__ Wx1, const void* __restrict__ bx1,
      const void* __restrict__ Wh1, const void* __restrict__ bh1,
      const void* __restrict__ Wo,  const void* __restrict__ bo,
      void* __restrict__ out,
      uint32_t* __restrict__ ws)
{
    extern __shared__ char smem[];
    if ((int)ws[FLG_OFF]) gru_body<true >(xin,Wx0,bx0,Wh0,bh0,Wx1,bx1,Wh1,bh1,Wo,bo,out,ws,smem);
    else                  gru_body<false>(xin,Wx0,bx0,Wh0,bh0,Wx1,bx1,Wh1,bh1,Wo,bo,out,ws,smem);
}

extern "C" void kernel_launch(void* const* d_in, const int* in_sizes, int n_in,
                              void* d_out, int out_size, void* d_ws, size_t ws_size,
                              hipStream_t stream) {
    uint32_t* ws  = (uint32_t*)d_ws;
    uint32_t* CTR = ws + CTR_OFF;
    uint32_t* FLG = ws + FLG_OFF;

    static bool attr_done = false;
    if (!attr_done) {
        hipFuncSetAttribute(reinterpret_cast<const void*>(gru12),
                            hipFuncAttributeMaxDynamicSharedMemorySize, 131072);
        attr_done = true;
    }

    probe_init<<<dim3(1), dim3(1024), 0, stream>>>((const uint32_t*)d_in[1], CTR, FLG);
    gru12<<<dim3(32), dim3(512), 114688, stream>>>(
        d_in[0], d_in[1], d_in[2], d_in[3], d_in[4],
        d_in[5], d_in[6], d_in[7], d_in[8], d_in[9], d_in[10],
        d_out, ws);
}